// Round 5
// baseline (246.102 us; speedup 1.0000x reference)
//
#include <hip/hip_runtime.h>

#define N_NODES 50000
#define N_EDGES 640000
#define IN_CH 128
#define OUT_CH 128
#define HID 256
#define M_PAD 50048                    // 1564 * 32
#define CAP 64                         // per-node edge capacity (Poisson(12.8): P(>=64)~1e-27)
#define BINS 196                       // ceil(50000/256) coarse dst bins
#define BIN_CAP 4096                   // mean 3277, sd 57 -> 14 sd margin
#define GEMM_GRID 512                  // persistent blocks (2/CU)

typedef unsigned int uint;
typedef unsigned short ushort;

// ---------- bf16 helpers (RNE) ----------
__device__ __forceinline__ ushort f2b(float f) {
    uint u = __float_as_uint(f);
    u += 0x7FFFu + ((u >> 16) & 1u);
    return (ushort)(u >> 16);
}
__device__ __forceinline__ float b2f_lo(uint u) { return __uint_as_float(u << 16); }
__device__ __forceinline__ float b2f_hi(uint u) { return __uint_as_float(u & 0xFFFF0000u); }
__device__ __forceinline__ uint packb(float lo, float hi) {
    return (uint)f2b(lo) | ((uint)f2b(hi) << 16);
}

// ---------- async global->LDS 16B ----------
__device__ __forceinline__ void gload_lds16(const ushort* g, ushort* l) {
    __builtin_amdgcn_global_load_lds(
        (const __attribute__((address_space(1))) void*)g,
        (__attribute__((address_space(3))) void*)l, 16, 0, 0);
}

// ================= prep: binned edge scatter + all casts, one dispatch =======
// blocks 0..2499: edges -> coarse bins. bin = dst>>8 (196 bins). Counter per
//   bin padded to its own 128B line (32-int stride) -> hot L2-resident atomic;
//   bin stores hit monotonically increasing addresses -> L2 write-combining
//   (vs round-1's 640K random 4B col stores = 50 MB sector-amplified writes).
// blocks 2500..6136: x cast -> xcat right half; weights -> fragment-major bf16
//   frag idx = ((n0*8 + kk)*64 + lane)*8 + j,
//   element  = W[n0*16 + (lane&15)][kk*32 + (lane>>4)*8 + j]
__global__ __launch_bounds__(256) void prep(
    const int* __restrict__ src, const int* __restrict__ dst,
    const float* __restrict__ x, const float* __restrict__ w1l,
    const float* __restrict__ w1r, const float* __restrict__ w2l,
    const float* __restrict__ w2r, int* __restrict__ bcnt,
    int2* __restrict__ bins, ushort* __restrict__ xcat,
    ushort* __restrict__ w1f, ushort* __restrict__ w2f) {
    int b = blockIdx.x;
    if (b < 2500) {
        int e = b * 256 + threadIdx.x;      // exactly 640000 threads
        int d = dst[e];
        int s = src[e];
        int bb = d >> 8;
        int p = atomicAdd(&bcnt[bb * 32], 1);
        if (p < BIN_CAP) bins[(size_t)bb * BIN_CAP + p] = make_int2(d, s);
    } else {
        int id = (b - 2500) * 256 + threadIdx.x;  // 0 .. 931071
        if (id < 800000) {                  // x: 8 floats/thread
            long long base = (long long)id * 8;
            float4 a = *(const float4*)(x + base);
            float4 c = *(const float4*)(x + base + 4);
            uint4 o;
            o.x = packb(a.x, a.y);
            o.y = packb(a.z, a.w);
            o.z = packb(c.x, c.y);
            o.w = packb(c.z, c.w);
            int row = id >> 4;
            int cc = id & 15;
            ((uint4*)xcat)[(size_t)row * 32 + 16 + cc] = o;
        } else if (id < 865536) {
            int i = id - 800000;
            int n0 = i >> 12, kk = (i >> 9) & 7, lane = (i >> 3) & 63, j = i & 7;
            int n = n0 * 16 + (lane & 15);
            int k = kk * 32 + (lane >> 4) * 8 + j;
            float v = (k < 128) ? w1l[k * 256 + n] : w1r[(k - 128) * 256 + n];
            w1f[i] = f2b(v);
        } else {
            int i = id - 865536;
            int n0 = i >> 12, kk = (i >> 9) & 7, lane = (i >> 3) & 63, j = i & 7;
            int n = n0 * 16 + (lane & 15);
            int k = kk * 32 + (lane >> 4) * 8 + j;
            float v = (n < 128) ? w2l[k * 128 + n] : w2r[k * 128 + (n - 128)];
            w2f[i] = f2b(v);
        }
    }
}

// ===== binplace: per-bin CSR build. LDS atomics for positions; col writes
// land in the bin's 64 KB window (L2-resident, line-friendly). ==============
__global__ __launch_bounds__(256) void binplace(
    const int* __restrict__ bcnt, const int2* __restrict__ bins,
    int* __restrict__ cnt, int* __restrict__ col) {
    __shared__ int lcnt[256];
    int b = blockIdx.x;
    lcnt[threadIdx.x] = 0;
    __syncthreads();
    int n = min(bcnt[b * 32], BIN_CAP);
    int base = b << 8;
    const int2* bb = bins + (size_t)b * BIN_CAP;
    for (int i = threadIdx.x; i < n; i += 256) {
        int2 e = bb[i];
        int p = atomicAdd(&lcnt[e.x - base], 1);
        if (p < CAP) col[(size_t)e.x * CAP + p] = e.y;
    }
    __syncthreads();
    int node = base + threadIdx.x;
    if (node < N_NODES) cnt[node] = lcnt[threadIdx.x];
}

// ====== layer-1 gather mean -> LEFT half of xcat; 16 thr/node, 4x unroll ======
__global__ __launch_bounds__(256) void aggregate_mean1(
    const int* __restrict__ cnt, const int* __restrict__ col,
    ushort* __restrict__ xcat) {
    int t = blockIdx.x * 256 + threadIdx.x;
    int node = t >> 4;
    int q = t & 15;
    if (node >= N_NODES) return;
    int degf = cnt[node];
    int deg = min(degf, CAP);
    const int* cb = col + node * CAP;
    float acc[8] = {0.f, 0.f, 0.f, 0.f, 0.f, 0.f, 0.f, 0.f};
    const uint4* f4 = (const uint4*)xcat;
    int j = 0;
    for (; j + 4 <= deg; j += 4) {
        int4 s4 = *(const int4*)(cb + j);
        uint4 v0 = f4[(size_t)s4.x * 32 + 16 + q];
        uint4 v1 = f4[(size_t)s4.y * 32 + 16 + q];
        uint4 v2 = f4[(size_t)s4.z * 32 + 16 + q];
        uint4 v3 = f4[(size_t)s4.w * 32 + 16 + q];
        acc[0] += b2f_lo(v0.x) + b2f_lo(v1.x) + b2f_lo(v2.x) + b2f_lo(v3.x);
        acc[1] += b2f_hi(v0.x) + b2f_hi(v1.x) + b2f_hi(v2.x) + b2f_hi(v3.x);
        acc[2] += b2f_lo(v0.y) + b2f_lo(v1.y) + b2f_lo(v2.y) + b2f_lo(v3.y);
        acc[3] += b2f_hi(v0.y) + b2f_hi(v1.y) + b2f_hi(v2.y) + b2f_hi(v3.y);
        acc[4] += b2f_lo(v0.z) + b2f_lo(v1.z) + b2f_lo(v2.z) + b2f_lo(v3.z);
        acc[5] += b2f_hi(v0.z) + b2f_hi(v1.z) + b2f_hi(v2.z) + b2f_hi(v3.z);
        acc[6] += b2f_lo(v0.w) + b2f_lo(v1.w) + b2f_lo(v2.w) + b2f_lo(v3.w);
        acc[7] += b2f_hi(v0.w) + b2f_hi(v1.w) + b2f_hi(v2.w) + b2f_hi(v3.w);
    }
    for (; j < deg; ++j) {
        uint4 v = f4[(size_t)cb[j] * 32 + 16 + q];
        acc[0] += b2f_lo(v.x); acc[1] += b2f_hi(v.x);
        acc[2] += b2f_lo(v.y); acc[3] += b2f_hi(v.y);
        acc[4] += b2f_lo(v.z); acc[5] += b2f_hi(v.z);
        acc[6] += b2f_lo(v.w); acc[7] += b2f_hi(v.w);
    }
    float inv = 1.0f / fmaxf((float)degf, 1.0f);
    uint4 o;
    o.x = packb(acc[0] * inv, acc[1] * inv);
    o.y = packb(acc[2] * inv, acc[3] * inv);
    o.z = packb(acc[4] * inv, acc[5] * inv);
    o.w = packb(acc[6] * inv, acc[7] * inv);
    ((uint4*)xcat)[(size_t)node * 32 + q] = o;
}

// ========== layer-2 combine: out = mean_gather(hw_l) + hw_r + bias ==========
__global__ __launch_bounds__(256) void combine2(
    const ushort* __restrict__ hw, const int* __restrict__ cnt,
    const int* __restrict__ col, const float* __restrict__ bias,
    float* __restrict__ out) {
    int t = blockIdx.x * 256 + threadIdx.x;
    int node = t >> 4;
    int q = t & 15;
    if (node >= N_NODES) return;
    int degf = cnt[node];
    int deg = min(degf, CAP);
    const int* cb = col + node * CAP;
    float acc[8] = {0.f, 0.f, 0.f, 0.f, 0.f, 0.f, 0.f, 0.f};
    const uint4* f4 = (const uint4*)hw;
    int j = 0;
    for (; j + 4 <= deg; j += 4) {
        int4 s4 = *(const int4*)(cb + j);
        uint4 v0 = f4[(size_t)s4.x * 32 + q];
        uint4 v1 = f4[(size_t)s4.y * 32 + q];
        uint4 v2 = f4[(size_t)s4.z * 32 + q];
        uint4 v3 = f4[(size_t)s4.w * 32 + q];
        acc[0] += b2f_lo(v0.x) + b2f_lo(v1.x) + b2f_lo(v2.x) + b2f_lo(v3.x);
        acc[1] += b2f_hi(v0.x) + b2f_hi(v1.x) + b2f_hi(v2.x) + b2f_hi(v3.x);
        acc[2] += b2f_lo(v0.y) + b2f_lo(v1.y) + b2f_lo(v2.y) + b2f_lo(v3.y);
        acc[3] += b2f_hi(v0.y) + b2f_hi(v1.y) + b2f_hi(v2.y) + b2f_hi(v3.y);
        acc[4] += b2f_lo(v0.z) + b2f_lo(v1.z) + b2f_lo(v2.z) + b2f_lo(v3.z);
        acc[5] += b2f_hi(v0.z) + b2f_hi(v1.z) + b2f_hi(v2.z) + b2f_hi(v3.z);
        acc[6] += b2f_lo(v0.w) + b2f_lo(v1.w) + b2f_lo(v2.w) + b2f_lo(v3.w);
        acc[7] += b2f_hi(v0.w) + b2f_hi(v1.w) + b2f_hi(v2.w) + b2f_hi(v3.w);
    }
    for (; j < deg; ++j) {
        uint4 v = f4[(size_t)cb[j] * 32 + q];
        acc[0] += b2f_lo(v.x); acc[1] += b2f_hi(v.x);
        acc[2] += b2f_lo(v.y); acc[3] += b2f_hi(v.y);
        acc[4] += b2f_lo(v.z); acc[5] += b2f_hi(v.z);
        acc[6] += b2f_lo(v.w); acc[7] += b2f_hi(v.w);
    }
    float inv = 1.0f / fmaxf((float)degf, 1.0f);
    uint4 r = f4[(size_t)node * 32 + 16 + q];
    float4 b0 = *(const float4*)(bias + q * 8);
    float4 b1 = *(const float4*)(bias + q * 8 + 4);
    float4 o0, o1;
    o0.x = acc[0] * inv + b2f_lo(r.x) + b0.x;
    o0.y = acc[1] * inv + b2f_hi(r.x) + b0.y;
    o0.z = acc[2] * inv + b2f_lo(r.y) + b0.z;
    o0.w = acc[3] * inv + b2f_hi(r.y) + b0.w;
    o1.x = acc[4] * inv + b2f_lo(r.z) + b1.x;
    o1.y = acc[5] * inv + b2f_hi(r.z) + b1.y;
    o1.z = acc[6] * inv + b2f_lo(r.w) + b1.z;
    o1.w = acc[7] * inv + b2f_hi(r.w) + b1.w;
    *(float4*)(out + (size_t)node * 128 + q * 8) = o0;
    *(float4*)(out + (size_t)node * 128 + q * 8 + 4) = o1;
}

// ============ persistent fused double GEMM, 32-row tiles, A double-buffered ==
// hw = relu(xcat @ W1 + b1) @ W2, all [*][256] bf16.
// 512 blocks x ~3 tiles. Per iter: issue next tile's gload_lds FIRST; the
// compiler's vmcnt(0)-before-barrier then lands AFTER GEMM1, so GEMM1's
// ~1-2us of MFMA covers the HBM stage latency (round-1 exposed it per block).
using bf16x8 = __attribute__((ext_vector_type(8))) short;
using f32x4  = __attribute__((ext_vector_type(4))) float;

__global__ __launch_bounds__(256) void fused_gemm(
    const ushort* __restrict__ A, const ushort* __restrict__ w1f,
    const ushort* __restrict__ w2f, const float* __restrict__ b1,
    ushort* __restrict__ hw) {
    __shared__ alignas(16) ushort buf[2][32 * 256];  // 2 x 16 KB

    const int tid = threadIdx.x;
    const int lane = tid & 63;
    const int wave = tid >> 6;
    const int quad = lane >> 4;
    const int l16 = lane & 15;
    const int srow = tid >> 5;          // staging row-in-group 0..7
    const int sc = tid & 31;            // staging chunk 0..31
    const int NT = M_PAD / 32;          // 1564

    const size_t bstep = 64 * 8;  // one kk step
    const ushort* w1b = w1f + (((size_t)(wave * 4) * 8) * 64 + lane) * 8;
    const ushort* w2b = w2f + (((size_t)(wave * 4) * 8) * 64 + lane) * 8;

    // ---- prologue: stage first tile into buf[0] ----
    {
        int t = blockIdx.x;
#pragma unroll
        for (int r = 0; r < 4; ++r) {
            int row = r * 8 + srow;
            int sl = (sc & 24) | ((sc & 7) ^ (row & 7));
            gload_lds16(A + (size_t)(t * 32 + row) * 256 + sl * 8,
                        &buf[0][row * 256 + sc * 8]);
        }
    }
    int cur = 0;
    __syncthreads();  // prologue stage drained

    for (int t = blockIdx.x; t < NT; t += GEMM_GRID) {
        ushort* tile = buf[cur];
        const int bm = t * 32;

        // ---- issue next tile's stage (drains at barrier-1, under GEMM1) ----
        int tn = t + GEMM_GRID;
        if (tn < NT) {
            ushort* nb = buf[cur ^ 1];
#pragma unroll
            for (int r = 0; r < 4; ++r) {
                int row = r * 8 + srow;
                int sl = (sc & 24) | ((sc & 7) ^ (row & 7));
                gload_lds16(A + (size_t)(tn * 32 + row) * 256 + sl * 8,
                            &nb[row * 256 + sc * 8]);
            }
        }

        f32x4 acc[2][4];
#pragma unroll
        for (int rt = 0; rt < 2; ++rt)
#pragma unroll
            for (int ct = 0; ct < 4; ++ct) acc[rt][ct] = (f32x4){0.f, 0.f, 0.f, 0.f};

        bf16x8 bc[4], bn[4];
#pragma unroll
        for (int ct = 0; ct < 4; ++ct)
            bc[ct] = *(const bf16x8*)(w1b + (size_t)ct * 8 * bstep);

        // ---- GEMM1 (tile already resident from previous iter's barrier) ----
#pragma unroll
        for (int kk = 0; kk < 8; ++kk) {
            if (kk < 7) {
#pragma unroll
                for (int ct = 0; ct < 4; ++ct)
                    bn[ct] = *(const bf16x8*)(w1b + ((size_t)ct * 8 + kk + 1) * bstep);
            }
            bf16x8 af[2];
#pragma unroll
            for (int rt = 0; rt < 2; ++rt) {
                int row = rt * 16 + l16;
                int c = kk * 4 + quad;
                int slot = (c & 24) | ((c & 7) ^ (row & 7));
                af[rt] = *(const bf16x8*)&tile[row * 256 + slot * 8];
            }
#pragma unroll
            for (int ct = 0; ct < 4; ++ct) {
#pragma unroll
                for (int rt = 0; rt < 2; ++rt)
                    acc[rt][ct] = __builtin_amdgcn_mfma_f32_16x16x32_bf16(
                        af[rt], bc[ct], acc[rt][ct], 0, 0, 0);
            }
#pragma unroll
            for (int ct = 0; ct < 4; ++ct) bc[ct] = bn[ct];
        }
        __syncthreads();  // (1) A reads done; next stage drained; reuse tile for h

        // ---- h = relu(acc + b1) -> tile (swizzled bf16) ----
#pragma unroll
        for (int ct = 0; ct < 4; ++ct) {
            int colg = wave * 64 + ct * 16 + l16;
            float bv = b1[colg];
            int cc = colg >> 3;
            int off = colg & 7;
#pragma unroll
            for (int rt = 0; rt < 2; ++rt) {
#pragma unroll
                for (int reg = 0; reg < 4; ++reg) {
                    int row = rt * 16 + quad * 4 + reg;
                    int slot = (cc & 24) | ((cc & 7) ^ (row & 7));
                    tile[row * 256 + slot * 8 + off] =
                        f2b(fmaxf(acc[rt][ct][reg] + bv, 0.0f));
                }
            }
        }

#pragma unroll
        for (int rt = 0; rt < 2; ++rt)
#pragma unroll
            for (int ct = 0; ct < 4; ++ct) acc[rt][ct] = (f32x4){0.f, 0.f, 0.f, 0.f};

#pragma unroll
        for (int ct = 0; ct < 4; ++ct)
            bc[ct] = *(const bf16x8*)(w2b + (size_t)ct * 8 * bstep);

        __syncthreads();  // (2) h visible

        // ---- GEMM2 ----
#pragma unroll
        for (int kk = 0; kk < 8; ++kk) {
            if (kk < 7) {
#pragma unroll
                for (int ct = 0; ct < 4; ++ct)
                    bn[ct] = *(const bf16x8*)(w2b + ((size_t)ct * 8 + kk + 1) * bstep);
            }
            bf16x8 af[2];
#pragma unroll
            for (int rt = 0; rt < 2; ++rt) {
                int row = rt * 16 + l16;
                int c = kk * 4 + quad;
                int slot = (c & 24) | ((c & 7) ^ (row & 7));
                af[rt] = *(const bf16x8*)&tile[row * 256 + slot * 8];
            }
#pragma unroll
            for (int ct = 0; ct < 4; ++ct) {
#pragma unroll
                for (int rt = 0; rt < 2; ++rt)
                    acc[rt][ct] = __builtin_amdgcn_mfma_f32_16x16x32_bf16(
                        af[rt], bc[ct], acc[rt][ct], 0, 0, 0);
            }
#pragma unroll
            for (int ct = 0; ct < 4; ++ct) bc[ct] = bn[ct];
        }
        __syncthreads();  // (3) h reads done; reuse tile for output

        // ---- out tile -> tile (swizzled), then coalesced dwordx4 store ----
#pragma unroll
        for (int ct = 0; ct < 4; ++ct) {
            int colg = wave * 64 + ct * 16 + l16;
            int cc = colg >> 3;
            int off = colg & 7;
#pragma unroll
            for (int rt = 0; rt < 2; ++rt) {
#pragma unroll
                for (int reg = 0; reg < 4; ++reg) {
                    int row = rt * 16 + quad * 4 + reg;
                    int slot = (cc & 24) | ((cc & 7) ^ (row & 7));
                    tile[row * 256 + slot * 8 + off] = f2b(acc[rt][ct][reg]);
                }
            }
        }
        __syncthreads();  // (4) out tile ready
#pragma unroll
        for (int r = 0; r < 4; ++r) {
            int row = r * 8 + srow;
            int slot = (sc & 24) | ((sc & 7) ^ (row & 7));
            uint4 v = *(const uint4*)&tile[row * 256 + slot * 8];
            *(uint4*)(hw + (size_t)(bm + row) * 256 + sc * 8) = v;
        }
        __syncthreads();  // (5) LDS reads of out tile done; tile free for next stage
        cur ^= 1;
    }
}

// ================= host =================
extern "C" void kernel_launch(void* const* d_in, const int* in_sizes, int n_in,
                              void* d_out, int out_size, void* d_ws, size_t ws_size,
                              hipStream_t stream) {
    const float* x    = (const float*)d_in[0];
    const int*   ei   = (const int*)d_in[1];
    const float* w1_l = (const float*)d_in[2];
    const float* b1_l = (const float*)d_in[3];
    const float* w1_r = (const float*)d_in[4];
    const float* w2_l = (const float*)d_in[5];
    const float* b2_l = (const float*)d_in[6];
    const float* w2_r = (const float*)d_in[7];
    float* out = (float*)d_out;

    const int* src = ei;
    const int* dst = ei + N_EDGES;

    // ---- workspace ----
    int* cnt = (int*)d_ws;                                   // [N]
    int* col = cnt + N_NODES;                                // [N*CAP] (12.8 MB)
    int* bcnt = col + (size_t)N_NODES * CAP;                 // [196*32] padded counters
    int2* bins = (int2*)(bcnt + BINS * 32);                  // [196*4096] (6.4 MB)
    size_t int_bytes = (size_t)(N_NODES + N_NODES * CAP + BINS * 32) * 4
                       + (size_t)BINS * BIN_CAP * 8;
    size_t ofs = ((size_t)((char*)bins - (char*)d_ws) + (size_t)BINS * BIN_CAP * 8 + 15)
                 & ~(size_t)15;
    (void)int_bytes;
    ushort* xcat = (ushort*)((char*)d_ws + ofs);             // [M_PAD][256]: mean1|x
    ushort* hw   = xcat + (size_t)M_PAD * HID;               // [M_PAD][256]
    ushort* w1f  = hw + (size_t)M_PAD * HID;                 // [16][8][64][8]
    ushort* w2f  = w1f + HID * HID;                          // [16][8][64][8]

    hipMemsetAsync(bcnt, 0, (size_t)BINS * 32 * sizeof(int), stream);

    // ---- binned edge scatter + casts (one dispatch), then per-bin CSR ----
    prep<<<2500 + 3637, 256, 0, stream>>>(src, dst, x, w1_l, w1_r, w2_l, w2_r,
                                          bcnt, bins, xcat, w1f, w2f);
    binplace<<<BINS, 256, 0, stream>>>(bcnt, bins, cnt, col);

    // ---- layer 1 gather, persistent fused double-GEMM, layer 2 combine ----
    aggregate_mean1<<<N_NODES * 16 / 256, 256, 0, stream>>>(cnt, col, xcat);
    fused_gemm<<<GEMM_GRID, 256, 0, stream>>>(xcat, w1f, w2f, b1_l, hw);
    combine2<<<N_NODES * 16 / 256, 256, 0, stream>>>(hw, cnt, col, b2_l, out);
}